// Round 5
// baseline (255.474 us; speedup 1.0000x reference)
//
#include <hip/hip_runtime.h>

// 3x3 conv, stride 1, pad 1, NCHW/OIHW fp32. N=16, C=32, OC=32, H=W=256.
//
// R8: 2x2 factorial A/B, store-policy x store-layout, via 4 quarter-grid
// dispatches (4 images each) that together compute the full output once.
//  Evidence so far: dur == hbm_bytes / 2.4 TB/s across FOUR structurally
//  different kernels (R4-R7); layout, duty-cycle, and wave-concurrency all
//  exonerated. The one constant since R4: nontemporal stores. Theory: nt
//  (no-allocate) bypasses L2 write-back aggregation -> temporally scattered
//  128B write transactions interleaved with reads at the DRAM controllers
//  -> ~2.4 TB/s wall. Plain stores let L2 batch + drain in address order
//  (m13's 6.3 TB/s copy is the existence proof for plain stores).
//  D0: NT+transposed (R7 control)   D1: plain+transposed
//  D2: plain+scattered (R5 epilog)  D3: NT+scattered
//  Each quarter: 512 blocks = full 2-block/CU residency, serialized on the
//  stream; per-dispatch rocprof rows give the A/B.

constexpr int N_  = 16;
constexpr int C_  = 32;
constexpr int OC_ = 32;
constexpr int H_  = 256;
constexpr int W_  = 256;

constexpr int XSTR = 20;             // ushorts per wi: 32B data (16 ic) + 8B pad
constexpr int XROW = 258 * XSTR;     // ushorts per staged row (wi = w+1)
constexpr int WSTRD = 36;            // ushorts per (t9,oc): 64B data + 8B pad
constexpr int WELEMS = 9 * 32 * WSTRD;   // 10368 ushorts
constexpr int WBYTES = WELEMS * 2;       // 20736 B (= 1296 x 16B exactly)

typedef __attribute__((ext_vector_type(4)))  short short4v;
typedef __attribute__((ext_vector_type(8)))  short short8v;
typedef __attribute__((ext_vector_type(16))) float float16v;
typedef __attribute__((ext_vector_type(4)))  float floatx4;

static __device__ __forceinline__ unsigned short f2bf(float f) {
    unsigned int u = __float_as_uint(f);
    unsigned int r = (u + 0x7FFFu + ((u >> 16) & 1u)) >> 16;   // RNE
    return (unsigned short)r;
}

// one instruction: dst.lo16 = bf16(lo), dst.hi16 = bf16(hi)
static __device__ __forceinline__ unsigned cvtpk(float lo, float hi) {
    unsigned r;
    asm("v_cvt_pk_bf16_f32 %0, %1, %2" : "=v"(r) : "v"(lo), "v"(hi));
    return r;
}

static __device__ __forceinline__ short8v load8(const unsigned short* p) {
    // 8B-aligned: two ds_read_b64
    short4v lo = *(const short4v*)p;
    short4v hi = *(const short4v*)(p + 4);
    return __builtin_shufflevector(lo, hi, 0, 1, 2, 3, 4, 5, 6, 7);
}

// ---- prep: swizzled bf16 weight image, computed once per launch ----
__global__ void conv_w_prep(const float* __restrict__ wgt,
                            unsigned short* __restrict__ wp) {
    const int i = blockIdx.x * 256 + threadIdx.x;
    if (i >= OC_ * C_ * 9) return;
    const float v = wgt[i];
    const int oc  = i / 288;
    const int rem = i - oc * 288;
    const int ic  = rem / 9;
    const int t9  = rem - ic * 9;
    wp[(t9 * 32 + oc) * WSTRD + ic] = f2bf(v);
}

template<bool USE_WS, bool NT, bool XPOSE>
__global__ __launch_bounds__(512, 4) void conv3x3_mfma_kernel(
    const float* __restrict__ x,     // [N][C][H][W]
    const float* __restrict__ wgt,   // [OC][C][3][3]
    const float* __restrict__ bias,  // [OC]
    const unsigned short* __restrict__ wpk,  // prepped weights (d_ws)
    float* __restrict__ out,         // [N][OC][H][W]
    int n0)                          // first image this dispatch covers
{
    __shared__ __align__(16) unsigned short ldsX[4 * XROW];   // 41,280 B
    __shared__ __align__(16) unsigned short ldsW[WELEMS];     // 20,736 B

    const int tid = threadIdx.x;

    // XCD-aware swizzle (works for any gridDim.x % 8 == 0)
    const int id  = blockIdx.x;
    const int cpx = gridDim.x >> 3;
    const int L   = (id & 7) * cpx + (id >> 3);
    const int n   = n0 + (L >> 7);   // image
    const int h   = (L & 127) * 2;   // output rows h, h+1

    const int lane = tid & 63;
    const int wv   = tid >> 6;       // wave 0..7
    const int rsel = wv >> 2;        // output row select (0/1)
    const int col  = lane & 31;      // A: oc; B/D: w col
    const int qd   = lane >> 5;      // k-quad select
    const int w0a  = (wv & 3) * 64;
    const int w0b  = (wv & 3) * 64 + 32;

    // staging map: thread -> (staged row r4, w-pair wlo, ic-quad icq)
    const int r4  = tid >> 7;        // staged input row 0..3 (= h-1+r4)
    const int t7  = tid & 127;
    const int wlo = t7 & 31;         // w-pair lane
    const int icq = t7 >> 5;         // 0..3 (handles ic-pairs icq and icq+4)
    const size_t HW = (size_t)H_ * W_;

    // ---- issue half0 x loads first (earliest possible) ----
    float2 a0[4], a1[4], b0r[4], b1r[4];
    auto load_half = [&](int half) {
        const int icg0 = half * 16 + 2 * icq;
        const int icg1 = half * 16 + 2 * (icq + 4);
        const int hy = h - 1 + r4;
        if (hy >= 0 && hy < H_) {
            const float* pA0 = x + ((size_t)(n * C_ + icg0) * H_ + hy) * W_;
            const float* pA1 = pA0 + HW;
            const float* pB0 = x + ((size_t)(n * C_ + icg1) * H_ + hy) * W_;
            const float* pB1 = pB0 + HW;
            #pragma unroll
            for (int wb = 0; wb < 4; ++wb) {
                const int w = wb * 64 + 2 * wlo;
                a0[wb]  = *(const float2*)(pA0 + w);
                a1[wb]  = *(const float2*)(pA1 + w);
                b0r[wb] = *(const float2*)(pB0 + w);
                b1r[wb] = *(const float2*)(pB1 + w);
            }
        } else {
            #pragma unroll
            for (int wb = 0; wb < 4; ++wb) {
                a0[wb] = a1[wb] = b0r[wb] = b1r[wb] = make_float2(0.f, 0.f);
            }
        }
    };
    load_half(0);

    // ---- weight stage ----
    if (USE_WS) {
        const int4* src = (const int4*)wpk;
        int4* dstW = (int4*)&ldsW[0];
        #pragma unroll
        for (int i2 = 0; i2 < 3; ++i2) {
            const int idx = tid + i2 * 512;
            if (idx < WBYTES / 16) dstW[idx] = src[idx];
        }
    } else {
        for (int i = tid; i < OC_ * C_ * 9; i += 512) {
            const float v = wgt[i];
            const int oc  = i / 288;
            const int rem = i - oc * 288;
            const int ic  = rem / 9;
            const int t9  = rem - ic * 9;
            ldsW[(t9 * 32 + oc) * WSTRD + ic] = f2bf(v);
        }
    }

    // ---- acc init with bias (D row = oc mapping, verified in R2) ----
    float16v acc0, acc1;
    #pragma unroll
    for (int r = 0; r < 16; ++r) {
        const float bv = bias[(r & 3) + 8 * (r >> 2) + 4 * qd];
        acc0[r] = bv;
        acc1[r] = bv;
    }

    auto write_half = [&]() {
        unsigned short* dst = &ldsX[r4 * XROW];
        #pragma unroll
        for (int wb = 0; wb < 4; ++wb) {
            const int w = wb * 64 + 2 * wlo;
            *(unsigned*)&dst[(w + 1) * XSTR + 2 * icq]       = cvtpk(a0[wb].x,  a1[wb].x);
            *(unsigned*)&dst[(w + 2) * XSTR + 2 * icq]       = cvtpk(a0[wb].y,  a1[wb].y);
            *(unsigned*)&dst[(w + 1) * XSTR + 2 * (icq + 4)] = cvtpk(b0r[wb].x, b1r[wb].x);
            *(unsigned*)&dst[(w + 2) * XSTR + 2 * (icq + 4)] = cvtpk(b0r[wb].y, b1r[wb].y);
        }
    };

    auto mfma_half = [&](int half) {
        #pragma unroll
        for (int kh = 0; kh < 3; ++kh) {
            #pragma unroll
            for (int kw = 0; kw < 3; ++kw) {
                const int t9 = kh * 3 + kw;
                const short8v av =
                    load8(&ldsW[(t9 * 32 + col) * WSTRD + half * 16 + qd * 8]);
                const short8v bf0 =
                    load8(&ldsX[(rsel + kh) * XROW + (w0a + col + kw) * XSTR + qd * 8]);
                const short8v bf1 =
                    load8(&ldsX[(rsel + kh) * XROW + (w0b + col + kw) * XSTR + qd * 8]);
                acc0 = __builtin_amdgcn_mfma_f32_32x32x16_bf16(av, bf0, acc0, 0, 0, 0);
                acc1 = __builtin_amdgcn_mfma_f32_32x32x16_bf16(av, bf1, acc1, 0, 0, 0);
            }
        }
    };

    // ---- pack + write half0; halo zeros (persist across both halves) ----
    write_half();
    if (tid < 32) {
        const int r  = tid >> 3;                 // staged row 0..3
        const int q  = tid & 7;
        const int wi = (q & 4) ? 257 : 0;
        const int c  = q & 3;
        *(unsigned long long*)&ldsX[r * XROW + wi * XSTR + c * 4] = 0ull;
    }
    __syncthreads();                 // X0 + W staged

    // half1 loads fly under MFMA half0; barrier #2's vmcnt(0) drains them
    load_half(1);
    mfma_half(0);
    __syncthreads();                 // MFMA0 readers done (and half1 loads landed)

    write_half();
    __syncthreads();                 // X1 staged
    mfma_half(1);

    // ---- epilogue ----
    if (XPOSE) {
        // LDS transpose -> fully contiguous 1KB-per-instr row stores
        __syncthreads();             // all frag reads of ldsX done
        float* scr = (float*)&ldsX[0];   // 32 KB scratch: [32 oc][256 w]
        #pragma unroll
        for (int rr = 0; rr < 2; ++rr) {
            if (rsel == rr) {        // wave-uniform branch
                #pragma unroll
                for (int r = 0; r < 16; ++r) {
                    const int oc = (r & 3) + 8 * (r >> 2) + 4 * qd;
                    scr[oc * 256 + w0a + col] = acc0[r];
                    scr[oc * 256 + w0b + col] = acc1[r];
                }
            }
            __syncthreads();
            float* outp = out + (size_t)n * OC_ * HW + (size_t)(h + rr) * W_;
            #pragma unroll
            for (int k = 0; k < 4; ++k) {
                const int oc = wv * 4 + k;
                const floatx4 v = *(const floatx4*)&scr[oc * 256 + lane * 4];
                floatx4* dp = (floatx4*)(outp + (size_t)oc * HW + lane * 4);
                if (NT) __builtin_nontemporal_store(v, dp);
                else    *dp = v;
            }
            if (rr == 0) __syncthreads();
        }
    } else {
        // scattered direct acc stores (R5 epilogue)
        float* outp = out + (size_t)n * OC_ * HW + (size_t)(h + rsel) * W_;
        #pragma unroll
        for (int r = 0; r < 16; ++r) {
            const int oc = (r & 3) + 8 * (r >> 2) + 4 * qd;
            float* p0 = &outp[(size_t)oc * HW + w0a + col];
            float* p1 = &outp[(size_t)oc * HW + w0b + col];
            if (NT) {
                __builtin_nontemporal_store(acc0[r], p0);
                __builtin_nontemporal_store(acc1[r], p1);
            } else {
                *p0 = acc0[r];
                *p1 = acc1[r];
            }
        }
    }
}

extern "C" void kernel_launch(void* const* d_in, const int* in_sizes, int n_in,
                              void* d_out, int out_size, void* d_ws, size_t ws_size,
                              hipStream_t stream) {
    const float* x    = (const float*)d_in[0];
    const float* wgt  = (const float*)d_in[1];
    const float* bias = (const float*)d_in[2];
    float* out        = (float*)d_out;

    dim3 block(512);

    if (d_ws != nullptr && ws_size >= (size_t)WBYTES) {
        unsigned short* wp = (unsigned short*)d_ws;
        conv_w_prep<<<dim3(36), dim3(256), 0, stream>>>(wgt, wp);
        // 4 quarter dispatches, 4 images each (512 blocks = 2/CU full
        // residency). Together they compute the complete output exactly once.
        dim3 q(512);
        conv3x3_mfma_kernel<true, true,  true ><<<q, block, 0, stream>>>(x, wgt, bias, wp, out,  0); // D0 NT+xpose (R7 ctl)
        conv3x3_mfma_kernel<true, false, true ><<<q, block, 0, stream>>>(x, wgt, bias, wp, out,  4); // D1 plain+xpose
        conv3x3_mfma_kernel<true, false, false><<<q, block, 0, stream>>>(x, wgt, bias, wp, out,  8); // D2 plain+scatter
        conv3x3_mfma_kernel<true, true,  false><<<q, block, 0, stream>>>(x, wgt, bias, wp, out, 12); // D3 NT+scatter
    } else {
        dim3 grid(N_ * H_ / 2);   // 2048 blocks, full problem
        conv3x3_mfma_kernel<false, true, true><<<grid, block, 0, stream>>>(x, wgt, bias, nullptr, out, 0);
    }
}